// Round 2
// baseline (976.056 us; speedup 1.0000x reference)
//
#include <hip/hip_runtime.h>

// Problem constants
#define B_   64
#define CH_  8
#define NBC  512        // B*CH
#define G_   256
#define K_   6
#define H_   251        // G-K+1
#define NP   256        // padded matrix dim
#define MAT  (NP*NP)    // 65536 elements per padded matrix

// ---------------- conv: x [64,256,256] -> Y chunk [cur,256,256] (zero-padded outside 251x251) ----------------
__global__ __launch_bounds__(256) void conv_kernel(const float* __restrict__ x,
                                                   const float* __restrict__ w,
                                                   const float* __restrict__ bias,
                                                   float* __restrict__ Y,
                                                   int bc_base) {
    int idx = blockIdx.x * 256 + threadIdx.x;      // cur*65536 total
    int lbc = idx >> 16;
    int bc = bc_base + lbc;
    int ij = idx & 65535;
    int i = ij >> 8;
    int j = ij & 255;
    int b = bc >> 3;
    int ch = bc & 7;
    float val = 0.0f;
    if (i < H_ && j < H_) {
        val = bias[ch];
        const float* xp = x + (size_t)b * (G_ * G_) + i * G_ + j;
        const float* wp = w + ch * (K_ * K_);
        #pragma unroll
        for (int u = 0; u < K_; ++u) {
            #pragma unroll
            for (int v = 0; v < K_; ++v) {
                val += xp[u * G_ + v] * wp[u * K_ + v];
            }
        }
    }
    Y[idx] = val;
}

// ---------------- GEMM1: M = Y*Y (per local bc), 64x64 tiles ----------------
__global__ __launch_bounds__(256) void gemm1(const float* __restrict__ Ybuf,
                                             float* __restrict__ Mbuf) {
    int bc = blockIdx.z;
    const float* A = Ybuf + (size_t)bc * MAT;
    const float* B = A;
    float* C = Mbuf + (size_t)bc * MAT;
    int bi = blockIdx.y * 64, bj = blockIdx.x * 64;

    __shared__ float As[16][64];   // As[k][i]
    __shared__ float Bs[16][64];   // Bs[k][j]

    int tid = threadIdx.x;
    int tx = tid & 15, ty = tid >> 4;
    float acc[4][4] = {};

    for (int k0 = 0; k0 < NP; k0 += 16) {
        {
            int i = tid >> 2;            // 0..63
            int k4 = (tid & 3) * 4;      // 0,4,8,12
            float4 av = *(const float4*)(A + (size_t)(bi + i) * NP + k0 + k4);
            As[k4 + 0][i] = av.x; As[k4 + 1][i] = av.y;
            As[k4 + 2][i] = av.z; As[k4 + 3][i] = av.w;
            int k = tid >> 4;            // 0..15
            int j4 = (tid & 15) * 4;
            *(float4*)(&Bs[k][j4]) = *(const float4*)(B + (size_t)(k0 + k) * NP + bj + j4);
        }
        __syncthreads();
        #pragma unroll
        for (int k = 0; k < 16; ++k) {
            float4 a = *(const float4*)(&As[k][ty * 4]);
            float4 b = *(const float4*)(&Bs[k][tx * 4]);
            float av[4] = {a.x, a.y, a.z, a.w};
            float bv[4] = {b.x, b.y, b.z, b.w};
            #pragma unroll
            for (int m = 0; m < 4; ++m)
                #pragma unroll
                for (int n = 0; n < 4; ++n)
                    acc[m][n] += av[m] * bv[n];
        }
        __syncthreads();
    }
    #pragma unroll
    for (int m = 0; m < 4; ++m) {
        float4 v = make_float4(acc[m][0], acc[m][1], acc[m][2], acc[m][3]);
        *(float4*)(C + (size_t)(bi + ty * 4 + m) * NP + bj + tx * 4) = v;
    }
}

// ---------------- trace pass: t2 = tr(M), t3 = sum M_ij*Y_ji, t4 = sum M_ij*M_ji ----------------
__global__ __launch_bounds__(256) void tracepass(const float* __restrict__ Mbuf,
                                                 const float* __restrict__ Ybuf,
                                                 double* __restrict__ traces,
                                                 int bc_base) {
    int lbc = blockIdx.x;
    int bc = bc_base + lbc;
    const float* M = Mbuf + (size_t)lbc * MAT;
    const float* Y = Ybuf + (size_t)lbc * MAT;
    int tid = threadIdx.x;

    float s2 = 0.0f, s3 = 0.0f, s4 = 0.0f;
    for (int i = 0; i < NP; ++i) {
        float mij = M[i * NP + tid];       // M[i][tid]
        s3 += mij * Y[tid * NP + i];       // * Y[tid][i]
        s4 += mij * M[tid * NP + i];       // * M[tid][i]
        if (tid == i) s2 += mij;           // diagonal
    }
    // wave reduce (64 lanes)
    #pragma unroll
    for (int off = 32; off > 0; off >>= 1) {
        s2 += __shfl_down(s2, off, 64);
        s3 += __shfl_down(s3, off, 64);
        s4 += __shfl_down(s4, off, 64);
    }
    __shared__ double red[3][4];
    int wid = tid >> 6;
    if ((tid & 63) == 0) {
        red[0][wid] = (double)s2;
        red[1][wid] = (double)s3;
        red[2][wid] = (double)s4;
    }
    __syncthreads();
    if (tid == 0) {
        traces[bc * 4 + 0] = red[0][0] + red[0][1] + red[0][2] + red[0][3];
        traces[bc * 4 + 1] = red[1][0] + red[1][1] + red[1][2] + red[1][3];
        traces[bc * 4 + 2] = red[2][0] + red[2][1] + red[2][2] + red[2][3];
    }
}

// ---------------- GEMM2: N = M*Y (not stored); partial5[bc][tile] = sum N_ij * M_ji over tile ----------------
__global__ __launch_bounds__(256) void gemm2(const float* __restrict__ Mbuf,
                                             const float* __restrict__ Ybuf,
                                             double* __restrict__ partial5,
                                             int bc_base) {
    int lbc = blockIdx.z;
    const float* A = Mbuf + (size_t)lbc * MAT;   // M
    const float* B = Ybuf + (size_t)lbc * MAT;   // Y
    int bi = blockIdx.y * 64, bj = blockIdx.x * 64;

    __shared__ float As[16][64];
    __shared__ float Bs[16][64];

    int tid = threadIdx.x;
    int tx = tid & 15, ty = tid >> 4;
    float acc[4][4] = {};

    for (int k0 = 0; k0 < NP; k0 += 16) {
        {
            int i = tid >> 2;
            int k4 = (tid & 3) * 4;
            float4 av = *(const float4*)(A + (size_t)(bi + i) * NP + k0 + k4);
            As[k4 + 0][i] = av.x; As[k4 + 1][i] = av.y;
            As[k4 + 2][i] = av.z; As[k4 + 3][i] = av.w;
            int k = tid >> 4;
            int j4 = (tid & 15) * 4;
            *(float4*)(&Bs[k][j4]) = *(const float4*)(B + (size_t)(k0 + k) * NP + bj + j4);
        }
        __syncthreads();
        #pragma unroll
        for (int k = 0; k < 16; ++k) {
            float4 a = *(const float4*)(&As[k][ty * 4]);
            float4 b = *(const float4*)(&Bs[k][tx * 4]);
            float av[4] = {a.x, a.y, a.z, a.w};
            float bv[4] = {b.x, b.y, b.z, b.w};
            #pragma unroll
            for (int m = 0; m < 4; ++m)
                #pragma unroll
                for (int n = 0; n < 4; ++n)
                    acc[m][n] += av[m] * bv[n];
        }
        __syncthreads();
    }
    // epilogue: sum_{m,n} N[r][c] * M[c][r], r = bi+ty*4+m, c = bj+tx*4+n
    float sum = 0.0f;
    #pragma unroll
    for (int m = 0; m < 4; ++m) {
        int r = bi + ty * 4 + m;
        #pragma unroll
        for (int n = 0; n < 4; ++n) {
            int c = bj + tx * 4 + n;
            sum += acc[m][n] * A[(size_t)c * NP + r];
        }
    }
    #pragma unroll
    for (int off = 32; off > 0; off >>= 1) sum += __shfl_down(sum, off, 64);
    __shared__ double red[4];
    int wid = tid >> 6;
    if ((tid & 63) == 0) red[wid] = (double)sum;
    __syncthreads();
    if (tid == 0) {
        int bc = bc_base + lbc;
        int tile = blockIdx.y * 4 + blockIdx.x;
        partial5[bc * 16 + tile] = red[0] + red[1] + red[2] + red[3];
    }
}

// ---------------- combine: out[b] = sum_{ch,i,j} coef * t_i^(j+1) / numel^(i+j+1) ----------------
__global__ void combine(const double* __restrict__ traces,
                        const double* __restrict__ partial5,
                        const float* __restrict__ coef,
                        float* __restrict__ out) {
    int b = threadIdx.x;
    if (b >= B_) return;
    const double numel = (double)(H_ * H_);
    double acc = 0.0;
    for (int ch = 0; ch < CH_; ++ch) {
        int bc = b * CH_ + ch;
        double t[4];
        t[0] = traces[bc * 4 + 0];
        t[1] = traces[bc * 4 + 1];
        t[2] = traces[bc * 4 + 2];
        double t5 = 0.0;
        #pragma unroll
        for (int k = 0; k < 16; ++k) t5 += partial5[bc * 16 + k];
        t[3] = t5;
        double npow_i = numel;                  // numel^(i+1)
        for (int i = 0; i < 4; ++i) {
            double tv = t[i];
            double p = tv;                      // tv^(j+1)
            double d = npow_i;                  // numel^(i+j+1)
            for (int j = 0; j < 3; ++j) {
                acc += (double)coef[ch * 12 + i * 3 + j] * (p / d);
                p *= tv;
                d *= numel;
            }
            npow_i *= numel;
        }
    }
    out[b] = (float)acc;
}

extern "C" void kernel_launch(void* const* d_in, const int* in_sizes, int n_in,
                              void* d_out, int out_size, void* d_ws, size_t ws_size,
                              hipStream_t stream) {
    const float* x    = (const float*)d_in[0];
    const float* w    = (const float*)d_in[1];
    const float* bias = (const float*)d_in[2];
    const float* coef = (const float*)d_in[3];
    float* out = (float*)d_out;

    // workspace layout: traces (512*4 doubles = 16KB) | partial5 (512*16 doubles = 64KB) | Y chunk | M chunk
    double* traces   = (double*)d_ws;
    double* partial5 = traces + (size_t)NBC * 4;
    const size_t head = 81920;   // 16KB + 64KB
    float* Ybase = (float*)((char*)d_ws + head);

    const size_t per_mat_bytes = (size_t)MAT * sizeof(float);   // 256 KB
    size_t avail = (ws_size > head) ? (ws_size - head) : 0;
    int NC = (int)(avail / (2 * per_mat_bytes));                // matrices per chunk
    if (NC > NBC) NC = NBC;
    if (NC < 1) NC = 1;

    float* Y = Ybase;
    float* M = Y + (size_t)NC * MAT;

    for (int bc0 = 0; bc0 < NBC; bc0 += NC) {
        int cur = NBC - bc0;
        if (cur > NC) cur = NC;
        conv_kernel<<<cur * 256, 256, 0, stream>>>(x, w, bias, Y, bc0);
        gemm1<<<dim3(4, 4, cur), 256, 0, stream>>>(Y, M);
        tracepass<<<cur, 256, 0, stream>>>(M, Y, traces, bc0);
        gemm2<<<dim3(4, 4, cur), 256, 0, stream>>>(M, Y, partial5, bc0);
    }
    combine<<<1, 64, 0, stream>>>(traces, partial5, coef, out);
}

// Round 3
// 420.291 us; speedup vs baseline: 2.3223x; 2.3223x over previous
//
#include <hip/hip_runtime.h>

typedef short short8 __attribute__((ext_vector_type(8)));
typedef float f32x4 __attribute__((ext_vector_type(4)));

#define B_    64
#define CH_   8
#define NBC   512
#define NP    256
#define MATU  65536      // elements per padded matrix
#define H_    251
#define PADX  73         // input tile LDS row stride (floats)
#define PADT  76         // transpose tile LDS row stride (u32)

__device__ inline unsigned short bf16r(float f){
    unsigned u = __float_as_uint(f);
    u += 0x7fffu + ((u >> 16) & 1u);
    return (unsigned short)(u >> 16);
}
__device__ inline float bf16f(unsigned short h){ return __uint_as_float(((unsigned)h) << 16); }
__device__ inline unsigned packsplit(float v){
    unsigned short h = bf16r(v);
    unsigned short l = bf16r(v - bf16f(h));
    return (((unsigned)h) << 16) | (unsigned)l;
}
__device__ inline float unpackf(unsigned u){
    return __uint_as_float(u & 0xffff0000u) + bf16f((unsigned short)(u & 0xffffu));
}

// ---------------- conv: x[b] -> Ypk (packed hi|lo) and YTpk (transposed), zero-padded to 256 ----------------
__global__ __launch_bounds__(256) void conv_pack(const float* __restrict__ x,
                                                 const float* __restrict__ w,
                                                 const float* __restrict__ bias,
                                                 unsigned* __restrict__ Ypk,
                                                 unsigned* __restrict__ YTpk,
                                                 int b_base) {
    __shared__ float xt[69 * PADX];
    __shared__ float wsm[288];
    __shared__ float bsm[8];
    __shared__ unsigned ldst[64 * PADT];

    int tid = threadIdx.x;
    int tile = blockIdx.x;              // 0..15
    int lb = blockIdx.y;                // local batch in chunk
    int b = b_base + lb;
    int r0 = (tile >> 2) * 64, c0 = (tile & 3) * 64;

    wsm[tid] = (tid < 288) ? w[tid] : 0.f;
    if (tid < 32) wsm[256 + tid] = w[256 + tid];
    if (tid < 8)  bsm[tid] = bias[tid];

    const float* xb = x + (size_t)b * 65536;
    for (int idx = tid; idx < 69 * PADX; idx += 256) {
        int row = idx / PADX, col = idx - row * PADX;
        float v = 0.f;
        if (col < 69) {
            int gr = r0 + row; if (gr > 255) gr = 255;
            int gc = c0 + col; if (gc > 255) gc = 255;
            v = xb[gr * 256 + gc];
        }
        xt[idx] = v;
    }
    __syncthreads();

    int tx = tid & 15, ty = tid >> 4;

    for (int ch = 0; ch < 8; ++ch) {
        float acc[4][4];
        float bv = bsm[ch];
        #pragma unroll
        for (int i = 0; i < 4; ++i)
            #pragma unroll
            for (int j = 0; j < 4; ++j) acc[i][j] = bv;

        const float* wc = &wsm[ch * 36];
        #pragma unroll
        for (int ir = 0; ir < 9; ++ir) {
            float row[9];
            #pragma unroll
            for (int c = 0; c < 9; ++c) row[c] = xt[(ty * 4 + ir) * PADX + tx * 4 + c];
            #pragma unroll
            for (int i = 0; i < 4; ++i) {
                int u = ir - i;
                if (u >= 0 && u < 6) {
                    #pragma unroll
                    for (int v = 0; v < 6; ++v) {
                        float wv = wc[u * 6 + v];
                        #pragma unroll
                        for (int j = 0; j < 4; ++j) acc[i][j] += row[j + v] * wv;
                    }
                }
            }
        }

        unsigned pk[4][4];
        #pragma unroll
        for (int i = 0; i < 4; ++i) {
            int gr = r0 + ty * 4 + i;
            #pragma unroll
            for (int j = 0; j < 4; ++j) {
                int gc = c0 + tx * 4 + j;
                float v = (gr < H_ && gc < H_) ? acc[i][j] : 0.f;
                pk[i][j] = packsplit(v);
            }
        }

        unsigned* yrow = Ypk + (size_t)(lb * 8 + ch) * MATU;
        #pragma unroll
        for (int i = 0; i < 4; ++i) {
            uint4 v = make_uint4(pk[i][0], pk[i][1], pk[i][2], pk[i][3]);
            *(uint4*)&yrow[(size_t)(r0 + ty * 4 + i) * 256 + c0 + tx * 4] = v;
        }

        // transpose via LDS
        #pragma unroll
        for (int j = 0; j < 4; ++j) {
            uint4 col = make_uint4(pk[0][j], pk[1][j], pk[2][j], pk[3][j]);
            *(uint4*)&ldst[(tx * 4 + j) * PADT + ty * 4] = col;
        }
        __syncthreads();
        unsigned* ytrow = YTpk + (size_t)(lb * 8 + ch) * MATU;
        {
            int cp = tid >> 2;           // 0..63 (row of YT tile)
            int qb = tid & 3;
            #pragma unroll
            for (int l2 = 0; l2 < 4; ++l2) {
                int q = l2 * 4 + qb;     // 0..15
                uint4 v = *(uint4*)&ldst[cp * PADT + q * 4];
                *(uint4*)&ytrow[(size_t)(c0 + cp) * 256 + r0 + q * 4] = v;
            }
        }
        __syncthreads();
    }
}

// ---------------- MFMA GEMM (split bf16, 3 chains). PHASE1: M=Y*Y, writes M/MT, t2/t3.
//                  PHASE2: M*M, t4/t5. B operand is given transposed (BT[col][k]). ----------------
template<int PHASE>
__global__ __launch_bounds__(256) void gemm_mfma(const unsigned* __restrict__ Apk,
                                                 const unsigned* __restrict__ Bpk,
                                                 unsigned* __restrict__ Mpk,
                                                 unsigned* __restrict__ MTpk,
                                                 const unsigned* __restrict__ YTpk,
                                                 double* __restrict__ pdiag,
                                                 double* __restrict__ pfull,
                                                 int bc_base) {
    __shared__ __align__(16) char smem[34816];     // stage 32KB; PHASE1 transpose [64][132]u32=33792B (union)
    __shared__ double redbuf[8];

    unsigned short* Ahi = (unsigned short*)smem;
    unsigned short* Alo = (unsigned short*)(smem + 8192);
    unsigned short* Bhi = (unsigned short*)(smem + 16384);
    unsigned short* Blo = (unsigned short*)(smem + 24576);

    int tid = threadIdx.x;
    int lbc = blockIdx.z;
    int bc = bc_base + lbc;
    const unsigned* A = Apk + (size_t)lbc * MATU;
    const unsigned* Bm = Bpk + (size_t)lbc * MATU;
    int bi = blockIdx.y * 128, bj = blockIdx.x * 128;

    int wid = tid >> 6, l = tid & 63;
    int wr = wid >> 1, wc = wid & 1;
    int l15 = l & 15, lk = l >> 4;

    f32x4 acc[4][4];
    #pragma unroll
    for (int m = 0; m < 4; ++m)
        #pragma unroll
        for (int n = 0; n < 4; ++n) acc[m][n] = (f32x4){0.f, 0.f, 0.f, 0.f};

    for (int k0 = 0; k0 < 256; k0 += 32) {
        #pragma unroll
        for (int p = 0; p < 4; ++p) {
            int g = p * 256 + tid;
            int row = g >> 3, chn = g & 7;
            uint4 qa = *(const uint4*)(A + (size_t)(bi + row) * 256 + k0 + chn * 4);
            ushort4 ha = make_ushort4(qa.x >> 16, qa.y >> 16, qa.z >> 16, qa.w >> 16);
            ushort4 la = make_ushort4(qa.x & 0xffff, qa.y & 0xffff, qa.z & 0xffff, qa.w & 0xffff);
            *(ushort4*)&Ahi[row * 32 + chn * 4] = ha;
            *(ushort4*)&Alo[row * 32 + chn * 4] = la;
            uint4 qb = *(const uint4*)(Bm + (size_t)(bj + row) * 256 + k0 + chn * 4);
            ushort4 hb = make_ushort4(qb.x >> 16, qb.y >> 16, qb.z >> 16, qb.w >> 16);
            ushort4 lb = make_ushort4(qb.x & 0xffff, qb.y & 0xffff, qb.z & 0xffff, qb.w & 0xffff);
            *(ushort4*)&Bhi[row * 32 + chn * 4] = hb;
            *(ushort4*)&Blo[row * 32 + chn * 4] = lb;
        }
        __syncthreads();

        short8 ah[4], al[4], bh[4], bl[4];
        #pragma unroll
        for (int m = 0; m < 4; ++m) {
            int r = wr * 64 + m * 16 + l15;
            ah[m] = *(const short8*)&Ahi[r * 32 + lk * 8];
            al[m] = *(const short8*)&Alo[r * 32 + lk * 8];
        }
        #pragma unroll
        for (int n = 0; n < 4; ++n) {
            int c = wc * 64 + n * 16 + l15;
            bh[n] = *(const short8*)&Bhi[c * 32 + lk * 8];
            bl[n] = *(const short8*)&Blo[c * 32 + lk * 8];
        }
        #pragma unroll
        for (int m = 0; m < 4; ++m)
            #pragma unroll
            for (int n = 0; n < 4; ++n) {
                acc[m][n] = __builtin_amdgcn_mfma_f32_16x16x32_bf16(ah[m], bh[n], acc[m][n], 0, 0, 0);
                acc[m][n] = __builtin_amdgcn_mfma_f32_16x16x32_bf16(ah[m], bl[n], acc[m][n], 0, 0, 0);
                acc[m][n] = __builtin_amdgcn_mfma_f32_16x16x32_bf16(al[m], bh[n], acc[m][n], 0, 0, 0);
            }
        __syncthreads();
    }

    // epilogue: partial traces (+ M/MT writes in PHASE1)
    const unsigned* YT = YTpk + (size_t)lbc * MATU;
    unsigned* Mw = (PHASE == 1) ? (Mpk + (size_t)lbc * MATU) : nullptr;
    float s_full = 0.f, s_diag = 0.f;
    #pragma unroll
    for (int m = 0; m < 4; ++m)
        #pragma unroll
        for (int n = 0; n < 4; ++n)
            #pragma unroll
            for (int reg = 0; reg < 4; ++reg) {
                float v = acc[m][n][reg];
                int rg = bi + wr * 64 + m * 16 + lk * 4 + reg;
                int cg = bj + wc * 64 + n * 16 + l15;
                float yv = unpackf(YT[(size_t)rg * 256 + cg]);   // Y[cg][rg]
                s_full += v * yv;
                if (rg == cg) s_diag += v;
                if (PHASE == 1) Mw[(size_t)rg * 256 + cg] = packsplit(v);
            }

    if (PHASE == 1) {
        // write MT via LDS transpose (two column-halves)
        unsigned* tr = (unsigned*)smem;
        unsigned* MT = MTpk + (size_t)lbc * MATU;
        for (int h = 0; h < 2; ++h) {
            __syncthreads();
            if (wc == h) {
                #pragma unroll
                for (int m = 0; m < 4; ++m)
                    #pragma unroll
                    for (int n = 0; n < 4; ++n)
                        #pragma unroll
                        for (int reg = 0; reg < 4; ++reg) {
                            int r_l = wr * 64 + m * 16 + lk * 4 + reg;
                            int c_l2 = n * 16 + l15;
                            tr[c_l2 * 132 + r_l] = packsplit(acc[m][n][reg]);
                        }
            }
            __syncthreads();
            int c2 = tid >> 2;
            int qb = tid & 3;
            #pragma unroll
            for (int lq = 0; lq < 8; ++lq) {
                int q = lq * 4 + qb;       // 0..31
                uint4 v = *(uint4*)&tr[c2 * 132 + q * 4];
                *(uint4*)&MT[(size_t)(bj + h * 64 + c2) * 256 + bi + q * 4] = v;
            }
        }
    }

    // reduce partials
    double df = (double)s_full, dd = (double)s_diag;
    #pragma unroll
    for (int off = 32; off > 0; off >>= 1) {
        df += __shfl_down(df, off, 64);
        dd += __shfl_down(dd, off, 64);
    }
    __syncthreads();
    if (l == 0) { redbuf[wid] = df; redbuf[4 + wid] = dd; }
    __syncthreads();
    if (tid == 0) {
        pfull[(size_t)bc * 4 + blockIdx.y * 2 + blockIdx.x] =
            redbuf[0] + redbuf[1] + redbuf[2] + redbuf[3];
        if (blockIdx.x == blockIdx.y)
            pdiag[(size_t)bc * 2 + blockIdx.x] =
                redbuf[4] + redbuf[5] + redbuf[6] + redbuf[7];
    }
}

// ---------------- combine ----------------
__global__ void combine(const double* __restrict__ p2, const double* __restrict__ p3,
                        const double* __restrict__ p4, const double* __restrict__ p5,
                        const float* __restrict__ coef, float* __restrict__ out) {
    int b = threadIdx.x;
    if (b >= B_) return;
    const double numel = (double)(H_ * H_);
    double acc = 0.0;
    for (int ch = 0; ch < CH_; ++ch) {
        int bc = b * CH_ + ch;
        double t[4];
        t[0] = p2[bc * 2] + p2[bc * 2 + 1];
        t[1] = p3[bc * 4] + p3[bc * 4 + 1] + p3[bc * 4 + 2] + p3[bc * 4 + 3];
        t[2] = p4[bc * 2] + p4[bc * 2 + 1];
        t[3] = p5[bc * 4] + p5[bc * 4 + 1] + p5[bc * 4 + 2] + p5[bc * 4 + 3];
        double npow_i = numel;
        for (int i = 0; i < 4; ++i) {
            double tv = t[i];
            double p = tv, d = npow_i;
            for (int j = 0; j < 3; ++j) {
                acc += (double)coef[ch * 12 + i * 3 + j] * (p / d);
                p *= tv;
                d *= numel;
            }
            npow_i *= numel;
        }
    }
    out[b] = (float)acc;
}

extern "C" void kernel_launch(void* const* d_in, const int* in_sizes, int n_in,
                              void* d_out, int out_size, void* d_ws, size_t ws_size,
                              hipStream_t stream) {
    const float* x    = (const float*)d_in[0];
    const float* w    = (const float*)d_in[1];
    const float* bias = (const float*)d_in[2];
    const float* coef = (const float*)d_in[3];
    float* out = (float*)d_out;

    // head: p2[512*2] p3[512*4] p4[512*2] p5[512*4] doubles (48KB) in first 64KB
    double* p2 = (double*)d_ws;
    double* p3 = p2 + NBC * 2;
    double* p4 = p3 + NBC * 4;
    double* p5 = p4 + NBC * 2;
    const size_t head = 65536;

    const size_t per_mat = (size_t)MATU * 4;                 // 256 KB per packed matrix
    size_t avail = (ws_size > head) ? ws_size - head : 0;
    int NC = (int)(avail / (4 * per_mat));                   // Y, YT, M, MT per matrix
    NC &= ~7;                                                // whole batches (8 channels)
    if (NC > NBC) NC = NBC;
    if (NC < 8) NC = 8;

    unsigned* Ypk  = (unsigned*)((char*)d_ws + head);
    unsigned* YTpk = Ypk  + (size_t)NC * MATU;
    unsigned* Mpk  = YTpk + (size_t)NC * MATU;
    unsigned* MTpk = Mpk  + (size_t)NC * MATU;

    for (int bc0 = 0; bc0 < NBC; bc0 += NC) {
        int cur = NBC - bc0;
        if (cur > NC) cur = NC;
        int nb = cur / 8;
        conv_pack<<<dim3(16, nb), 256, 0, stream>>>(x, w, bias, Ypk, YTpk, bc0 / 8);
        gemm_mfma<1><<<dim3(2, 2, cur), 256, 0, stream>>>(Ypk, YTpk, Mpk, MTpk, YTpk, p2, p3, bc0);
        gemm_mfma<2><<<dim3(2, 2, cur), 256, 0, stream>>>(Mpk, MTpk, nullptr, nullptr, YTpk, p4, p5, bc0);
    }
    combine<<<1, 64, 0, stream>>>(p2, p3, p4, p5, coef, out);
}

// Round 6
// 408.929 us; speedup vs baseline: 2.3869x; 1.0278x over previous
//
#include <hip/hip_runtime.h>

typedef short short8 __attribute__((ext_vector_type(8)));
typedef float f32x4 __attribute__((ext_vector_type(4)));

#define B_    64
#define CH_   8
#define NBC   512
#define NP    256
#define MATU  65536      // elements per padded matrix
#define H_    251
#define PADX  73         // input tile LDS row stride (floats)
#define PADT  76         // transpose tile LDS row stride (u32)

__device__ inline unsigned short bf16r(float f){
    unsigned u = __float_as_uint(f);
    u += 0x7fffu + ((u >> 16) & 1u);
    return (unsigned short)(u >> 16);
}
__device__ inline float bf16f(unsigned short h){ return __uint_as_float(((unsigned)h) << 16); }
__device__ inline unsigned packsplit(float v){
    unsigned short h = bf16r(v);
    unsigned short l = bf16r(v - bf16f(h));
    return (((unsigned)h) << 16) | (unsigned)l;
}
__device__ inline float unpackf(unsigned u){
    return __uint_as_float(u & 0xffff0000u) + bf16f((unsigned short)(u & 0xffffu));
}

// ---------------- conv: x[b] -> Ypk (packed hi|lo) and YTpk (transposed), zero-padded to 256 ----------------
__global__ __launch_bounds__(256) void conv_pack(const float* __restrict__ x,
                                                 const float* __restrict__ w,
                                                 const float* __restrict__ bias,
                                                 unsigned* __restrict__ Ypk,
                                                 unsigned* __restrict__ YTpk,
                                                 int b_base) {
    __shared__ float xt[69 * PADX];
    __shared__ float wsm[288];
    __shared__ float bsm[8];
    __shared__ unsigned ldst[64 * PADT];

    int tid = threadIdx.x;
    int tile = blockIdx.x;              // 0..15
    int lb = blockIdx.y;                // local batch in chunk
    int b = b_base + lb;
    int r0 = (tile >> 2) * 64, c0 = (tile & 3) * 64;

    wsm[tid] = (tid < 288) ? w[tid] : 0.f;
    if (tid < 32) wsm[256 + tid] = w[256 + tid];
    if (tid < 8)  bsm[tid] = bias[tid];

    const float* xb = x + (size_t)b * 65536;
    for (int idx = tid; idx < 69 * PADX; idx += 256) {
        int row = idx / PADX, col = idx - row * PADX;
        float v = 0.f;
        if (col < 69) {
            int gr = r0 + row; if (gr > 255) gr = 255;
            int gc = c0 + col; if (gc > 255) gc = 255;
            v = xb[gr * 256 + gc];
        }
        xt[idx] = v;
    }
    __syncthreads();

    int tx = tid & 15, ty = tid >> 4;

    for (int ch = 0; ch < 8; ++ch) {
        float acc[4][4];
        float bv = bsm[ch];
        #pragma unroll
        for (int i = 0; i < 4; ++i)
            #pragma unroll
            for (int j = 0; j < 4; ++j) acc[i][j] = bv;

        const float* wc = &wsm[ch * 36];
        #pragma unroll
        for (int ir = 0; ir < 9; ++ir) {
            float row[9];
            #pragma unroll
            for (int c = 0; c < 9; ++c) row[c] = xt[(ty * 4 + ir) * PADX + tx * 4 + c];
            #pragma unroll
            for (int i = 0; i < 4; ++i) {
                int u = ir - i;
                if (u >= 0 && u < 6) {
                    #pragma unroll
                    for (int v = 0; v < 6; ++v) {
                        float wv = wc[u * 6 + v];
                        #pragma unroll
                        for (int j = 0; j < 4; ++j) acc[i][j] += row[j + v] * wv;
                    }
                }
            }
        }

        unsigned pk[4][4];
        #pragma unroll
        for (int i = 0; i < 4; ++i) {
            int gr = r0 + ty * 4 + i;
            #pragma unroll
            for (int j = 0; j < 4; ++j) {
                int gc = c0 + tx * 4 + j;
                float v = (gr < H_ && gc < H_) ? acc[i][j] : 0.f;
                pk[i][j] = packsplit(v);
            }
        }

        unsigned* yrow = Ypk + (size_t)(lb * 8 + ch) * MATU;
        #pragma unroll
        for (int i = 0; i < 4; ++i) {
            uint4 v = make_uint4(pk[i][0], pk[i][1], pk[i][2], pk[i][3]);
            *(uint4*)&yrow[(size_t)(r0 + ty * 4 + i) * 256 + c0 + tx * 4] = v;
        }

        // transpose via LDS
        #pragma unroll
        for (int j = 0; j < 4; ++j) {
            uint4 col = make_uint4(pk[0][j], pk[1][j], pk[2][j], pk[3][j]);
            *(uint4*)&ldst[(tx * 4 + j) * PADT + ty * 4] = col;
        }
        __syncthreads();
        unsigned* ytrow = YTpk + (size_t)(lb * 8 + ch) * MATU;
        {
            int cp = tid >> 2;           // 0..63 (row of YT tile)
            int qb = tid & 3;
            #pragma unroll
            for (int l2 = 0; l2 < 4; ++l2) {
                int q = l2 * 4 + qb;     // 0..15
                uint4 v = *(uint4*)&ldst[cp * PADT + q * 4];
                *(uint4*)&ytrow[(size_t)(c0 + cp) * 256 + r0 + q * 4] = v;
            }
        }
        __syncthreads();
    }
}

// ---------------- MFMA GEMM (split bf16, 3 chains). PHASE1: M=Y*Y, writes M/MT, t2/t3.
//                  PHASE2: M*M, t4/t5. B operand is given transposed (BT[col][k]). ----------------
template<int PHASE>
__global__ __launch_bounds__(256) void gemm_mfma(const unsigned* __restrict__ Apk,
                                                 const unsigned* __restrict__ Bpk,
                                                 unsigned* __restrict__ Mpk,
                                                 unsigned* __restrict__ MTpk,
                                                 const unsigned* __restrict__ YTpk,
                                                 double* __restrict__ pdiag,
                                                 double* __restrict__ pfull,
                                                 int bc_base) {
    __shared__ __align__(16) char smem[34816];     // stage 32KB; PHASE1 transpose [64][132]u32=33792B (union)
    __shared__ double redbuf[8];

    unsigned short* Ahi = (unsigned short*)smem;
    unsigned short* Alo = (unsigned short*)(smem + 8192);
    unsigned short* Bhi = (unsigned short*)(smem + 16384);
    unsigned short* Blo = (unsigned short*)(smem + 24576);

    int tid = threadIdx.x;
    int lbc = blockIdx.z;
    int bc = bc_base + lbc;
    const unsigned* A = Apk + (size_t)lbc * MATU;
    const unsigned* Bm = Bpk + (size_t)lbc * MATU;
    int bi = blockIdx.y * 128, bj = blockIdx.x * 128;

    int wid = tid >> 6, l = tid & 63;
    int wr = wid >> 1, wc = wid & 1;
    int l15 = l & 15, lk = l >> 4;

    f32x4 acc[4][4];
    #pragma unroll
    for (int m = 0; m < 4; ++m)
        #pragma unroll
        for (int n = 0; n < 4; ++n) acc[m][n] = (f32x4){0.f, 0.f, 0.f, 0.f};

    for (int k0 = 0; k0 < 256; k0 += 32) {
        #pragma unroll
        for (int p = 0; p < 4; ++p) {
            int g = p * 256 + tid;
            int row = g >> 3, chn = g & 7;
            uint4 qa = *(const uint4*)(A + (size_t)(bi + row) * 256 + k0 + chn * 4);
            ushort4 ha = make_ushort4(qa.x >> 16, qa.y >> 16, qa.z >> 16, qa.w >> 16);
            ushort4 la = make_ushort4(qa.x & 0xffff, qa.y & 0xffff, qa.z & 0xffff, qa.w & 0xffff);
            *(ushort4*)&Ahi[row * 32 + chn * 4] = ha;
            *(ushort4*)&Alo[row * 32 + chn * 4] = la;
            uint4 qb = *(const uint4*)(Bm + (size_t)(bj + row) * 256 + k0 + chn * 4);
            ushort4 hb = make_ushort4(qb.x >> 16, qb.y >> 16, qb.z >> 16, qb.w >> 16);
            ushort4 lb = make_ushort4(qb.x & 0xffff, qb.y & 0xffff, qb.z & 0xffff, qb.w & 0xffff);
            *(ushort4*)&Bhi[row * 32 + chn * 4] = hb;
            *(ushort4*)&Blo[row * 32 + chn * 4] = lb;
        }
        __syncthreads();

        short8 ah[4], al[4], bh[4], bl[4];
        #pragma unroll
        for (int m = 0; m < 4; ++m) {
            int r = wr * 64 + m * 16 + l15;
            ah[m] = *(const short8*)&Ahi[r * 32 + lk * 8];
            al[m] = *(const short8*)&Alo[r * 32 + lk * 8];
        }
        #pragma unroll
        for (int n = 0; n < 4; ++n) {
            int c = wc * 64 + n * 16 + l15;
            bh[n] = *(const short8*)&Bhi[c * 32 + lk * 8];
            bl[n] = *(const short8*)&Blo[c * 32 + lk * 8];
        }
        #pragma unroll
        for (int m = 0; m < 4; ++m)
            #pragma unroll
            for (int n = 0; n < 4; ++n) {
                acc[m][n] = __builtin_amdgcn_mfma_f32_16x16x32_bf16(ah[m], bh[n], acc[m][n], 0, 0, 0);
                acc[m][n] = __builtin_amdgcn_mfma_f32_16x16x32_bf16(ah[m], bl[n], acc[m][n], 0, 0, 0);
                acc[m][n] = __builtin_amdgcn_mfma_f32_16x16x32_bf16(al[m], bh[n], acc[m][n], 0, 0, 0);
            }
        __syncthreads();
    }

    // epilogue: partial traces (+ M/MT writes in PHASE1)
    const unsigned* YT = YTpk + (size_t)lbc * MATU;
    unsigned* Mw = (PHASE == 1) ? (Mpk + (size_t)lbc * MATU) : nullptr;
    float s_full = 0.f, s_diag = 0.f;
    #pragma unroll
    for (int m = 0; m < 4; ++m)
        #pragma unroll
        for (int n = 0; n < 4; ++n)
            #pragma unroll
            for (int reg = 0; reg < 4; ++reg) {
                float v = acc[m][n][reg];
                int rg = bi + wr * 64 + m * 16 + lk * 4 + reg;
                int cg = bj + wc * 64 + n * 16 + l15;
                float yv = unpackf(YT[(size_t)rg * 256 + cg]);   // Y[cg][rg]
                s_full += v * yv;
                if (rg == cg) s_diag += v;
                if (PHASE == 1) Mw[(size_t)rg * 256 + cg] = packsplit(v);
            }

    if (PHASE == 1) {
        // write MT via LDS transpose (two column-halves)
        unsigned* tr = (unsigned*)smem;
        unsigned* MT = MTpk + (size_t)lbc * MATU;
        for (int h = 0; h < 2; ++h) {
            __syncthreads();
            if (wc == h) {
                #pragma unroll
                for (int m = 0; m < 4; ++m)
                    #pragma unroll
                    for (int n = 0; n < 4; ++n)
                        #pragma unroll
                        for (int reg = 0; reg < 4; ++reg) {
                            int r_l = wr * 64 + m * 16 + lk * 4 + reg;
                            int c_l2 = n * 16 + l15;
                            tr[c_l2 * 132 + r_l] = packsplit(acc[m][n][reg]);
                        }
            }
            __syncthreads();
            int c2 = tid >> 2;
            int qb = tid & 3;
            #pragma unroll
            for (int lq = 0; lq < 8; ++lq) {
                int q = lq * 4 + qb;       // 0..31
                uint4 v = *(uint4*)&tr[c2 * 132 + q * 4];
                *(uint4*)&MT[(size_t)(bj + h * 64 + c2) * 256 + bi + q * 4] = v;
            }
        }
    }

    // reduce partials
    double df = (double)s_full, dd = (double)s_diag;
    #pragma unroll
    for (int off = 32; off > 0; off >>= 1) {
        df += __shfl_down(df, off, 64);
        dd += __shfl_down(dd, off, 64);
    }
    __syncthreads();
    if (l == 0) { redbuf[wid] = df; redbuf[4 + wid] = dd; }
    __syncthreads();
    if (tid == 0) {
        pfull[(size_t)bc * 4 + blockIdx.y * 2 + blockIdx.x] =
            redbuf[0] + redbuf[1] + redbuf[2] + redbuf[3];
        if (blockIdx.x == blockIdx.y)
            pdiag[(size_t)bc * 2 + blockIdx.x] =
                redbuf[4] + redbuf[5] + redbuf[6] + redbuf[7];
    }
}

// ---------------- combine ----------------
__global__ void combine(const double* __restrict__ p2, const double* __restrict__ p3,
                        const double* __restrict__ p4, const double* __restrict__ p5,
                        const float* __restrict__ coef, float* __restrict__ out) {
    int b = threadIdx.x;
    if (b >= B_) return;
    const double numel = (double)(H_ * H_);
    double acc = 0.0;
    for (int ch = 0; ch < CH_; ++ch) {
        int bc = b * CH_ + ch;
        double t[4];
        t[0] = p2[bc * 2] + p2[bc * 2 + 1];
        t[1] = p3[bc * 4] + p3[bc * 4 + 1] + p3[bc * 4 + 2] + p3[bc * 4 + 3];
        t[2] = p4[bc * 2] + p4[bc * 2 + 1];
        t[3] = p5[bc * 4] + p5[bc * 4 + 1] + p5[bc * 4 + 2] + p5[bc * 4 + 3];
        double npow_i = numel;
        for (int i = 0; i < 4; ++i) {
            double tv = t[i];
            double p = tv, d = npow_i;
            for (int j = 0; j < 3; ++j) {
                acc += (double)coef[ch * 12 + i * 3 + j] * (p / d);
                p *= tv;
                d *= numel;
            }
            npow_i *= numel;
        }
    }
    out[b] = (float)acc;
}

extern "C" void kernel_launch(void* const* d_in, const int* in_sizes, int n_in,
                              void* d_out, int out_size, void* d_ws, size_t ws_size,
                              hipStream_t stream) {
    const float* x    = (const float*)d_in[0];
    const float* w    = (const float*)d_in[1];
    const float* bias = (const float*)d_in[2];
    const float* coef = (const float*)d_in[3];
    float* out = (float*)d_out;

    // head: p2[512*2] p3[512*4] p4[512*2] p5[512*4] doubles (48KB) in first 64KB
    double* p2 = (double*)d_ws;
    double* p3 = p2 + NBC * 2;
    double* p4 = p3 + NBC * 4;
    double* p5 = p4 + NBC * 2;
    const size_t head = 65536;

    const size_t per_mat = (size_t)MATU * 4;                 // 256 KB per packed matrix
    size_t avail = (ws_size > head) ? ws_size - head : 0;
    int NC = (int)(avail / (4 * per_mat));                   // Y, YT, M, MT per matrix
    NC &= ~7;                                                // whole batches (8 channels)
    if (NC > 128) NC = 128;                                  // L3-residency cap: chunk WS = NC*1MB <= 128MB << 256MB LLC
    if (NC > NBC) NC = NBC;
    if (NC < 8) NC = 8;

    unsigned* Ypk  = (unsigned*)((char*)d_ws + head);
    unsigned* YTpk = Ypk  + (size_t)NC * MATU;
    unsigned* Mpk  = YTpk + (size_t)NC * MATU;
    unsigned* MTpk = Mpk  + (size_t)NC * MATU;

    for (int bc0 = 0; bc0 < NBC; bc0 += NC) {
        int cur = NBC - bc0;
        if (cur > NC) cur = NC;
        int nb = cur / 8;
        conv_pack<<<dim3(16, nb), 256, 0, stream>>>(x, w, bias, Ypk, YTpk, bc0 / 8);
        gemm_mfma<1><<<dim3(2, 2, cur), 256, 0, stream>>>(Ypk, YTpk, Mpk, MTpk, YTpk, p2, p3, bc0);
        gemm_mfma<2><<<dim3(2, 2, cur), 256, 0, stream>>>(Mpk, MTpk, nullptr, nullptr, YTpk, p4, p5, bc0);
    }
    combine<<<1, 64, 0, stream>>>(p2, p3, p4, p5, coef, out);
}

// Round 8
// 288.300 us; speedup vs baseline: 3.3856x; 1.4184x over previous
//
#include <hip/hip_runtime.h>

typedef short short8 __attribute__((ext_vector_type(8)));
typedef float f32x4 __attribute__((ext_vector_type(4)));

#define B_    64
#define CH_   8
#define NBC   512
#define MATU  65536      // elements per padded 256x256 matrix
#define H_    251
#define PADX  73         // conv input tile LDS row stride (floats)
#define LDSW  40         // LDS row stride in ushort (80B, 16B-aligned, 2-way-max frag-read conflicts)

__device__ inline unsigned short bf16r(float f){
    unsigned u = __float_as_uint(f);
    u += 0x7fffu + ((u >> 16) & 1u);
    return (unsigned short)(u >> 16);
}
__device__ inline float bf16f(unsigned short h){ return __uint_as_float(((unsigned)h) << 16); }
__device__ inline unsigned packsplit(float v){
    unsigned short h = bf16r(v);
    unsigned short l = bf16r(v - bf16f(h));
    return (((unsigned)h) << 16) | (unsigned)l;
}
__device__ inline float unpackf(unsigned u){
    return __uint_as_float(u & 0xffff0000u) + bf16f((unsigned short)(u & 0xffffu));
}

// ---------------- conv: x[b] -> Ypk (packed hi|lo u32, row-major), zero-padded to 256 ----------------
__global__ __launch_bounds__(256) void conv_pack(const float* __restrict__ x,
                                                 const float* __restrict__ w,
                                                 const float* __restrict__ bias,
                                                 unsigned* __restrict__ Ypk,
                                                 int b_base) {
    __shared__ float xt[69 * PADX];
    __shared__ float wsm[296];

    int tid = threadIdx.x;
    int tile = blockIdx.x;              // 0..15
    int lb = blockIdx.y;                // local batch in chunk
    int b = b_base + lb;
    int r0 = (tile >> 2) * 64, c0 = (tile & 3) * 64;

    // 288 weight floats with 256 threads: two statements (BUG in r7: single if(tid<288) covered only 0..255)
    wsm[tid] = w[tid];
    if (tid < 32) wsm[256 + tid] = w[256 + tid];
    if (tid < 8)  wsm[288 + tid] = bias[tid];

    const float* xb = x + (size_t)b * 65536;
    for (int idx = tid; idx < 69 * PADX; idx += 256) {
        int row = idx / PADX, col = idx - row * PADX;
        float v = 0.f;
        if (col < 69) {
            int gr = r0 + row; if (gr > 255) gr = 255;
            int gc = c0 + col; if (gc > 255) gc = 255;
            v = xb[gr * 256 + gc];
        }
        xt[idx] = v;
    }
    __syncthreads();

    int tx = tid & 15, ty = tid >> 4;

    for (int ch = 0; ch < 8; ++ch) {
        float acc[4][4];
        float bv = wsm[288 + ch];
        #pragma unroll
        for (int i = 0; i < 4; ++i)
            #pragma unroll
            for (int j = 0; j < 4; ++j) acc[i][j] = bv;

        const float* wc = &wsm[ch * 36];
        #pragma unroll
        for (int ir = 0; ir < 9; ++ir) {
            float row[9];
            #pragma unroll
            for (int c = 0; c < 9; ++c) row[c] = xt[(ty * 4 + ir) * PADX + tx * 4 + c];
            #pragma unroll
            for (int i = 0; i < 4; ++i) {
                int u = ir - i;
                if (u >= 0 && u < 6) {
                    #pragma unroll
                    for (int v = 0; v < 6; ++v) {
                        float wv = wc[u * 6 + v];
                        #pragma unroll
                        for (int j = 0; j < 4; ++j) acc[i][j] += row[j + v] * wv;
                    }
                }
            }
        }

        unsigned pk[4][4];
        #pragma unroll
        for (int i = 0; i < 4; ++i) {
            int gr = r0 + ty * 4 + i;
            #pragma unroll
            for (int j = 0; j < 4; ++j) {
                int gc = c0 + tx * 4 + j;
                float v = (gr < H_ && gc < H_) ? acc[i][j] : 0.f;
                pk[i][j] = packsplit(v);
            }
        }

        unsigned* yrow = Ypk + (size_t)(lb * 8 + ch) * MATU;
        #pragma unroll
        for (int i = 0; i < 4; ++i) {
            uint4 v = make_uint4(pk[i][0], pk[i][1], pk[i][2], pk[i][3]);
            *(uint4*)&yrow[(size_t)(r0 + ty * 4 + i) * 256 + c0 + tx * 4] = v;
        }
    }
}

// ---------------- MFMA GEMM out = X*X (split bf16, 3 chains), X = Apk (row-major packed).
// B-operand transpose-staged in LDS from the same row-major plane.
// PHASE1 (X=Y): writes M row-major; pdiag=t2=tr(M), pfull=t3=sum M_ij*Y_ji
// PHASE2 (X=M): no writes;          pdiag=t4,       pfull=t5=sum (M*M)_ij*Y_ji
template<int PHASE>
__global__ __launch_bounds__(256) void gemm_mfma(const unsigned* __restrict__ Apk,
                                                 const unsigned* __restrict__ Ypk,
                                                 unsigned* __restrict__ Mpk,
                                                 double* __restrict__ pdiag,
                                                 double* __restrict__ pfull,
                                                 int bc_base, int cur) {
    __shared__ __align__(16) char smem[4 * 128 * LDSW * 2];   // 40960B: Ahi|Alo|Bhi|Blo, each [128][LDSW] ushort
    __shared__ double redbuf[8];

    unsigned short* Ahi = (unsigned short*)smem;
    unsigned short* Alo = (unsigned short*)(smem + 10240);
    unsigned short* Bhi = (unsigned short*)(smem + 20480);
    unsigned short* Blo = (unsigned short*)(smem + 30720);

    int tid = threadIdx.x;

    // XCD-colocating bijective remap: a matrix's 4 tiles land on one XCD, close in dispatch order.
    // hw = s*8 + xcd ; lbc = xcd*(cur/8) + (s>>2) ; tile = s&3.  (cur is always a multiple of 8)
    int hw = blockIdx.x;
    int xcd = hw & 7, s = hw >> 3;
    int mpx = cur >> 3;
    int lbc = xcd * mpx + (s >> 2);
    int t4 = s & 3;
    int by = t4 >> 1, bx = t4 & 1;
    int bi = by * 128, bj = bx * 128;
    int bc = bc_base + lbc;

    const unsigned* A = Apk + (size_t)lbc * MATU;

    int wid = tid >> 6, l = tid & 63;
    int wr = wid >> 1, wc = wid & 1;
    int l15 = l & 15, lk = l >> 4;

    f32x4 acc[4][4];
    #pragma unroll
    for (int m = 0; m < 4; ++m)
        #pragma unroll
        for (int n = 0; n < 4; ++n) acc[m][n] = (f32x4){0.f, 0.f, 0.f, 0.f};

    const int colq = (tid & 31) * 4;     // B-stage: column quad
    const int kq   = (tid >> 5) * 4;     // B-stage: k quad

    for (int k0 = 0; k0 < 256; k0 += 32) {
        // ---- A stage: rows bi..bi+127, k0..k0+31, unpack u32 -> hi/lo planes ----
        #pragma unroll
        for (int p = 0; p < 4; ++p) {
            int g = p * 256 + tid;
            int row = g >> 3, chn = g & 7;
            uint4 qa = *(const uint4*)(A + (size_t)(bi + row) * 256 + k0 + chn * 4);
            *(ushort4*)&Ahi[row * LDSW + chn * 4] =
                make_ushort4(qa.x >> 16, qa.y >> 16, qa.z >> 16, qa.w >> 16);
            *(ushort4*)&Alo[row * LDSW + chn * 4] =
                make_ushort4(qa.x & 0xffff, qa.y & 0xffff, qa.z & 0xffff, qa.w & 0xffff);
        }
        // ---- B stage (transpose): B[k][bj+col] -> Bhi[col][k] ----
        {
            const unsigned* Bp = A + (size_t)(k0 + kq) * 256 + bj + colq;
            uint4 q0 = *(const uint4*)(Bp);
            uint4 q1 = *(const uint4*)(Bp + 256);
            uint4 q2 = *(const uint4*)(Bp + 512);
            uint4 q3 = *(const uint4*)(Bp + 768);
            *(ushort4*)&Bhi[(colq + 0) * LDSW + kq] =
                make_ushort4(q0.x >> 16, q1.x >> 16, q2.x >> 16, q3.x >> 16);
            *(ushort4*)&Blo[(colq + 0) * LDSW + kq] =
                make_ushort4(q0.x & 0xffff, q1.x & 0xffff, q2.x & 0xffff, q3.x & 0xffff);
            *(ushort4*)&Bhi[(colq + 1) * LDSW + kq] =
                make_ushort4(q0.y >> 16, q1.y >> 16, q2.y >> 16, q3.y >> 16);
            *(ushort4*)&Blo[(colq + 1) * LDSW + kq] =
                make_ushort4(q0.y & 0xffff, q1.y & 0xffff, q2.y & 0xffff, q3.y & 0xffff);
            *(ushort4*)&Bhi[(colq + 2) * LDSW + kq] =
                make_ushort4(q0.z >> 16, q1.z >> 16, q2.z >> 16, q3.z >> 16);
            *(ushort4*)&Blo[(colq + 2) * LDSW + kq] =
                make_ushort4(q0.z & 0xffff, q1.z & 0xffff, q2.z & 0xffff, q3.z & 0xffff);
            *(ushort4*)&Bhi[(colq + 3) * LDSW + kq] =
                make_ushort4(q0.w >> 16, q1.w >> 16, q2.w >> 16, q3.w >> 16);
            *(ushort4*)&Blo[(colq + 3) * LDSW + kq] =
                make_ushort4(q0.w & 0xffff, q1.w & 0xffff, q2.w & 0xffff, q3.w & 0xffff);
        }
        __syncthreads();

        short8 ah[4], al[4], bh[4], bl[4];
        #pragma unroll
        for (int m = 0; m < 4; ++m) {
            int r = wr * 64 + m * 16 + l15;
            ah[m] = *(const short8*)&Ahi[r * LDSW + lk * 8];
            al[m] = *(const short8*)&Alo[r * LDSW + lk * 8];
        }
        #pragma unroll
        for (int n = 0; n < 4; ++n) {
            int c = wc * 64 + n * 16 + l15;
            bh[n] = *(const short8*)&Bhi[c * LDSW + lk * 8];
            bl[n] = *(const short8*)&Blo[c * LDSW + lk * 8];
        }
        #pragma unroll
        for (int m = 0; m < 4; ++m)
            #pragma unroll
            for (int n = 0; n < 4; ++n) {
                acc[m][n] = __builtin_amdgcn_mfma_f32_16x16x32_bf16(ah[m], bh[n], acc[m][n], 0, 0, 0);
                acc[m][n] = __builtin_amdgcn_mfma_f32_16x16x32_bf16(ah[m], bl[n], acc[m][n], 0, 0, 0);
                acc[m][n] = __builtin_amdgcn_mfma_f32_16x16x32_bf16(al[m], bh[n], acc[m][n], 0, 0, 0);
            }
        __syncthreads();
    }

    // ---- epilogue: partial traces (+ M write in PHASE1); Y_ji read from row-major Y (contiguous 16B) ----
    const unsigned* Yb = Ypk + (size_t)lbc * MATU;
    unsigned* Mw = (PHASE == 1) ? (Mpk + (size_t)lbc * MATU) : nullptr;
    float s_full = 0.f, s_diag = 0.f;
    #pragma unroll
    for (int m = 0; m < 4; ++m) {
        int rg0 = bi + wr * 64 + m * 16 + lk * 4;
        #pragma unroll
        for (int n = 0; n < 4; ++n) {
            int cg = bj + wc * 64 + n * 16 + l15;
            uint4 yq = *(const uint4*)(Yb + (size_t)cg * 256 + rg0);   // Y[cg][rg0..rg0+3]
            unsigned yu[4] = {yq.x, yq.y, yq.z, yq.w};
            f32x4 v = acc[m][n];
            #pragma unroll
            for (int reg = 0; reg < 4; ++reg) {
                float val = v[reg];
                s_full += val * unpackf(yu[reg]);
                if (rg0 + reg == cg) s_diag += val;
                if (PHASE == 1) Mw[(size_t)(rg0 + reg) * 256 + cg] = packsplit(val);
            }
        }
    }

    // reduce partials
    double df = (double)s_full, dd = (double)s_diag;
    #pragma unroll
    for (int off = 32; off > 0; off >>= 1) {
        df += __shfl_down(df, off, 64);
        dd += __shfl_down(dd, off, 64);
    }
    __syncthreads();
    if (l == 0) { redbuf[wid] = df; redbuf[4 + wid] = dd; }
    __syncthreads();
    if (tid == 0) {
        pfull[(size_t)bc * 4 + by * 2 + bx] =
            redbuf[0] + redbuf[1] + redbuf[2] + redbuf[3];
        if (bx == by)
            pdiag[(size_t)bc * 2 + bx] =
                redbuf[4] + redbuf[5] + redbuf[6] + redbuf[7];
    }
}

// ---------------- combine ----------------
__global__ void combine(const double* __restrict__ p2, const double* __restrict__ p3,
                        const double* __restrict__ p4, const double* __restrict__ p5,
                        const float* __restrict__ coef, float* __restrict__ out) {
    int b = threadIdx.x;
    if (b >= B_) return;
    const double numel = (double)(H_ * H_);
    double acc = 0.0;
    for (int ch = 0; ch < CH_; ++ch) {
        int bc = b * CH_ + ch;
        double t[4];
        t[0] = p2[bc * 2] + p2[bc * 2 + 1];
        t[1] = p3[bc * 4] + p3[bc * 4 + 1] + p3[bc * 4 + 2] + p3[bc * 4 + 3];
        t[2] = p4[bc * 2] + p4[bc * 2 + 1];
        t[3] = p5[bc * 4] + p5[bc * 4 + 1] + p5[bc * 4 + 2] + p5[bc * 4 + 3];
        double npow_i = numel;
        for (int i = 0; i < 4; ++i) {
            double tv = t[i];
            double p = tv, d = npow_i;
            for (int j = 0; j < 3; ++j) {
                acc += (double)coef[ch * 12 + i * 3 + j] * (p / d);
                p *= tv;
                d *= numel;
            }
            npow_i *= numel;
        }
    }
    out[b] = (float)acc;
}

extern "C" void kernel_launch(void* const* d_in, const int* in_sizes, int n_in,
                              void* d_out, int out_size, void* d_ws, size_t ws_size,
                              hipStream_t stream) {
    const float* x    = (const float*)d_in[0];
    const float* w    = (const float*)d_in[1];
    const float* bias = (const float*)d_in[2];
    const float* coef = (const float*)d_in[3];
    float* out = (float*)d_out;

    // head: p2[512*2] p3[512*4] p4[512*2] p5[512*4] doubles (48KB) in first 64KB
    double* p2 = (double*)d_ws;
    double* p3 = p2 + NBC * 2;
    double* p4 = p3 + NBC * 4;
    double* p5 = p4 + NBC * 2;
    const size_t head = 65536;

    const size_t per_mat = (size_t)MATU * 4;                 // 256 KB per packed matrix plane
    size_t avail = (ws_size > head) ? ws_size - head : 0;
    int NC = (int)(avail / (2 * per_mat));                   // Y + M per matrix (512 KB)
    NC &= ~7;                                                // whole batches of 8 channels
    if (NC > 256) NC = 256;                                  // chunk WS = NC*0.5MB <= 128MB (L3) ; grid 4*NC <= 1024
    if (NC < 8) NC = 8;

    unsigned* Ypk = (unsigned*)((char*)d_ws + head);
    unsigned* Mpk = Ypk + (size_t)NC * MATU;

    for (int bc0 = 0; bc0 < NBC; bc0 += NC) {
        int cur = NBC - bc0;
        if (cur > NC) cur = NC;
        int nb = cur / 8;
        conv_pack<<<dim3(16, nb), 256, 0, stream>>>(x, w, bias, Ypk, bc0 / 8);
        // G1: M = Y*Y ; t2 = tr(M), t3 = sum M_ij * Y_ji
        gemm_mfma<1><<<cur * 4, 256, 0, stream>>>(Ypk, Ypk, Mpk, p2, p3, bc0, cur);
        // G2: P = M*M ; t4 = tr(P), t5 = sum P_ij * Y_ji
        gemm_mfma<2><<<cur * 4, 256, 0, stream>>>(Mpk, Ypk, nullptr, p4, p5, bc0, cur);
    }
    combine<<<1, 64, 0, stream>>>(p2, p3, p4, p5, coef, out);
}